// Round 2
// baseline (408.572 us; speedup 1.0000x reference)
//
#include <hip/hip_runtime.h>
#include <stdint.h>

#define NN 100000
#define NE 1600000
#define C  128

typedef __attribute__((ext_vector_type(8))) short short8;
typedef __attribute__((ext_vector_type(4))) float f32x4;

__device__ __forceinline__ float bf2f(uint16_t u) {
  union { uint32_t u; float f; } v; v.u = ((uint32_t)u) << 16; return v.f;
}
__device__ __forceinline__ uint16_t f2bf(float f) {
  union { float f; uint32_t u; } v; v.f = f;
  uint32_t r = v.u + 0x7fffu + ((v.u >> 16) & 1u);   // RNE
  return (uint16_t)(r >> 16);
}

// ---------------- cast f32 -> bf16, 4 elems/thread ----------------
__global__ __launch_bounds__(256) void cast_f32_bf16(
    const float* __restrict__ src, uint16_t* __restrict__ dst, int n4)
{
  int i = blockIdx.x * 256 + threadIdx.x;
  if (i < n4) {
    float4 v = ((const float4*)src)[i];
    uint2 p;
    p.x = (uint32_t)f2bf(v.x) | ((uint32_t)f2bf(v.y) << 16);
    p.y = (uint32_t)f2bf(v.z) | ((uint32_t)f2bf(v.w) << 16);
    ((uint2*)dst)[i] = p;
  }
}

// ---------------- GEMM1: h = relu(x @ Wp^T + bp), bf16 MFMA ----------------
// one wave = 16 rows x 128 cols; A/B frags: lane holds row/col (lane&15),
// k = (lane>>4)*8 + j (8 contiguous bf16 = 16B load)
__global__ __launch_bounds__(256) void gemm_proj_k(
    const uint16_t* __restrict__ xb, const uint16_t* __restrict__ wpb,
    const float* __restrict__ bias, uint16_t* __restrict__ h)
{
  const int wid = (blockIdx.x * 256 + threadIdx.x) >> 6;
  const int tile_m = wid * 16;
  if (tile_m >= NN) return;
  const int lane = threadIdx.x & 63;
  const int r16 = lane & 15, g = lane >> 4;

  short8 a[4];
  const uint16_t* ap = xb + (size_t)(tile_m + r16) * C + g * 8;
#pragma unroll
  for (int kk = 0; kk < 4; ++kk) a[kk] = *(const short8*)(ap + kk * 32);

#pragma unroll
  for (int nt = 0; nt < 8; ++nt) {
    f32x4 acc = {0.f, 0.f, 0.f, 0.f};
    const uint16_t* bpp = wpb + (size_t)(nt * 16 + r16) * C + g * 8;
#pragma unroll
    for (int kk = 0; kk < 4; ++kk) {
      short8 b = *(const short8*)(bpp + kk * 32);
      acc = __builtin_amdgcn_mfma_f32_16x16x32_bf16(a[kk], b, acc, 0, 0, 0);
    }
    const int col = nt * 16 + r16;
    const float bv = bias[col];
#pragma unroll
    for (int r = 0; r < 4; ++r) {
      int row = tile_m + g * 4 + r;          // C/D: col=lane&15, row=(lane>>4)*4+r
      float v = acc[r] + bv;
      v = v > 0.f ? v : 0.f;
      h[(size_t)row * C + col] = f2bf(v);
    }
  }
}

// ---------------- histogram of dst ----------------
__global__ __launch_bounds__(256) void hist_k(
    const int* __restrict__ dst, int* __restrict__ deg)
{
  int e = blockIdx.x * 256 + threadIdx.x;   // grid == NE exactly
  atomicAdd(&deg[dst[e]], 1);
}

// ---------------- 3-phase exclusive scan ----------------
__global__ __launch_bounds__(1024) void scan_block_k(
    const int* __restrict__ in, int* __restrict__ out, int* __restrict__ bsum, int n)
{
  __shared__ int sm[1024];
  int t = threadIdx.x;
  int i = blockIdx.x * 1024 + t;
  int v = (i < n) ? in[i] : 0;
  sm[t] = v;
  __syncthreads();
  for (int off = 1; off < 1024; off <<= 1) {
    int x = (t >= off) ? sm[t - off] : 0;
    __syncthreads();
    sm[t] += x;
    __syncthreads();
  }
  if (i < n) out[i] = sm[t] - v;            // exclusive within block
  if (t == 1023 && bsum) bsum[blockIdx.x] = sm[t];
}

__global__ __launch_bounds__(1024) void scan_add_k(
    int* __restrict__ start, const int* __restrict__ bsum,
    int* __restrict__ cursor, int n)
{
  int i = blockIdx.x * 1024 + threadIdx.x;
  if (i < n) {
    int s = start[i] + bsum[blockIdx.x];
    start[i] = s;
    cursor[i] = s;
  }
}

// ---------------- reorder: counting-sort edges by dst ----------------
__global__ __launch_bounds__(256) void reorder_k(
    const int* __restrict__ src, const int* __restrict__ dst,
    int* __restrict__ cursor, int* __restrict__ ssrc)
{
  int e = blockIdx.x * 256 + threadIdx.x;   // grid == NE exactly
  int d = dst[e];
  int pos = atomicAdd(&cursor[d], 1);
  ssrc[pos] = src[e];
}

// ---------------- atomic-free aggregation: 1 wave per node ----------------
__global__ __launch_bounds__(256) void aggregate_k(
    const uint16_t* __restrict__ h, const int* __restrict__ ssrc,
    const int* __restrict__ start, const int* __restrict__ deg,
    uint16_t* __restrict__ agg)
{
  int wid = (blockIdx.x * 256 + threadIdx.x) >> 6;
  if (wid >= NN) return;
  int lane = threadIdx.x & 63;
  int s0 = start[wid];
  int cnt = deg[wid];
  float a0 = 0.f, a1 = 0.f, b0 = 0.f, b1 = 0.f;
  int j = 0;
  for (; j + 2 <= cnt; j += 2) {            // unroll-2 for load ILP
    int sA = ssrc[s0 + j], sB = ssrc[s0 + j + 1];
    uint32_t vA = *(const uint32_t*)(h + (size_t)sA * C + lane * 2);
    uint32_t vB = *(const uint32_t*)(h + (size_t)sB * C + lane * 2);
    a0 += bf2f((uint16_t)vA); a1 += bf2f((uint16_t)(vA >> 16));
    b0 += bf2f((uint16_t)vB); b1 += bf2f((uint16_t)(vB >> 16));
  }
  if (j < cnt) {
    int sA = ssrc[s0 + j];
    uint32_t vA = *(const uint32_t*)(h + (size_t)sA * C + lane * 2);
    a0 += bf2f((uint16_t)vA); a1 += bf2f((uint16_t)(vA >> 16));
  }
  a0 += b0; a1 += b1;
  uint32_t p = (uint32_t)f2bf(a0) | ((uint32_t)f2bf(a1) << 16);
  *(uint32_t*)(agg + (size_t)wid * C + lane * 2) = p;
}

// ---------------- GEMM2 + LayerNorm fused ----------------
// out = LN(agg@Wl^T + x@Wr^T + bl)*gamma + beta ; one wave = 16 rows x 128 cols
__global__ __launch_bounds__(256) void gemm_out_k(
    const uint16_t* __restrict__ aggb, const uint16_t* __restrict__ xb,
    const uint16_t* __restrict__ wlb, const uint16_t* __restrict__ wrb,
    const float* __restrict__ bl, const float* __restrict__ gamma,
    const float* __restrict__ beta, float* __restrict__ out)
{
  const int wid = (blockIdx.x * 256 + threadIdx.x) >> 6;
  const int tile_m = wid * 16;
  if (tile_m >= NN) return;
  const int lane = threadIdx.x & 63;
  const int r16 = lane & 15, g = lane >> 4;

  short8 a0[4], a1[4];
  const uint16_t* p0 = aggb + (size_t)(tile_m + r16) * C + g * 8;
  const uint16_t* p1 = xb   + (size_t)(tile_m + r16) * C + g * 8;
#pragma unroll
  for (int kk = 0; kk < 4; ++kk) {
    a0[kk] = *(const short8*)(p0 + kk * 32);
    a1[kk] = *(const short8*)(p1 + kk * 32);
  }

  f32x4 acc[8];
#pragma unroll
  for (int nt = 0; nt < 8; ++nt) {
    f32x4 c = {0.f, 0.f, 0.f, 0.f};
    const uint16_t* bpl = wlb + (size_t)(nt * 16 + r16) * C + g * 8;
    const uint16_t* bpr = wrb + (size_t)(nt * 16 + r16) * C + g * 8;
#pragma unroll
    for (int kk = 0; kk < 4; ++kk)
      c = __builtin_amdgcn_mfma_f32_16x16x32_bf16(a0[kk], *(const short8*)(bpl + kk * 32), c, 0, 0, 0);
#pragma unroll
    for (int kk = 0; kk < 4; ++kk)
      c = __builtin_amdgcn_mfma_f32_16x16x32_bf16(a1[kk], *(const short8*)(bpr + kk * 32), c, 0, 0, 0);
    const float bv = bl[nt * 16 + r16];
#pragma unroll
    for (int r = 0; r < 4; ++r) c[r] += bv;
    acc[nt] = c;
  }

  // LayerNorm: each row lives in one 16-lane group -> shfl_xor 1,2,4,8
  float s1[4], s2[4];
#pragma unroll
  for (int r = 0; r < 4; ++r) { s1[r] = 0.f; s2[r] = 0.f; }
#pragma unroll
  for (int nt = 0; nt < 8; ++nt)
#pragma unroll
    for (int r = 0; r < 4; ++r) { float v = acc[nt][r]; s1[r] += v; s2[r] += v * v; }
#pragma unroll
  for (int m = 1; m <= 8; m <<= 1) {
#pragma unroll
    for (int r = 0; r < 4; ++r) {
      s1[r] += __shfl_xor(s1[r], m, 64);
      s2[r] += __shfl_xor(s2[r], m, 64);
    }
  }
  float mean[4], rstd[4];
#pragma unroll
  for (int r = 0; r < 4; ++r) {
    mean[r] = s1[r] * (1.f / C);
    float var = s2[r] * (1.f / C) - mean[r] * mean[r];
    rstd[r] = rsqrtf(var + 1e-5f);
  }
#pragma unroll
  for (int nt = 0; nt < 8; ++nt) {
    const int col = nt * 16 + r16;
    const float gmv = gamma[col], btv = beta[col];
#pragma unroll
    for (int r = 0; r < 4; ++r) {
      int row = tile_m + g * 4 + r;
      out[(size_t)row * C + col] = (acc[nt][r] - mean[r]) * rstd[r] * gmv + btv;
    }
  }
}

// ---------------- launch ----------------
extern "C" void kernel_launch(void* const* d_in, const int* in_sizes, int n_in,
                              void* d_out, int out_size, void* d_ws, size_t ws_size,
                              hipStream_t stream)
{
  const float* x        = (const float*)d_in[0];
  const int* ei         = (const int*)d_in[1];     // harness delivers integer inputs as int32
  const float* Wp       = (const float*)d_in[2];
  const float* bp       = (const float*)d_in[3];
  const float* Wl       = (const float*)d_in[4];
  const float* bl       = (const float*)d_in[5];
  const float* Wr       = (const float*)d_in[6];
  const float* gamma    = (const float*)d_in[7];
  const float* beta     = (const float*)d_in[8];
  float* out            = (float*)d_out;

  char* ws = (char*)d_ws;
  // ws layout (bytes), all 16B-aligned; total ~84.5 MB
  uint16_t* xb   = (uint16_t*)(ws + 0);          // 25,600,000  x as bf16
  uint16_t* h    = (uint16_t*)(ws + 25600000);   // 25,600,000  relu(proj) bf16
  uint16_t* aggb = (uint16_t*)(ws + 51200000);   // 25,600,000  agg bf16
  uint16_t* wpb  = (uint16_t*)(ws + 76800000);   // 32,768
  uint16_t* wlb  = (uint16_t*)(ws + 76832768);   // 32,768
  uint16_t* wrb  = (uint16_t*)(ws + 76865536);   // 32,768
  int* deg       = (int*)(ws + 76898304);        // 400,000
  int* start     = (int*)(ws + 77298304);        // 400,000
  int* cursor    = (int*)(ws + 77698304);        // 400,000
  int* bsum      = (int*)(ws + 78098304);        // 4,096
  int* ssrc      = (int*)(ws + 78102400);        // 6,400,000

  const int* esrc = ei;        // edge_index[0]
  const int* edst = ei + NE;   // edge_index[1]

  hipMemsetAsync(deg, 0, NN * sizeof(int), stream);

  cast_f32_bf16<<<(NN * C / 4 + 255) / 256, 256, 0, stream>>>(x, xb, NN * C / 4);
  cast_f32_bf16<<<(C * C / 4 + 255) / 256, 256, 0, stream>>>(Wp, wpb, C * C / 4);
  cast_f32_bf16<<<(C * C / 4 + 255) / 256, 256, 0, stream>>>(Wl, wlb, C * C / 4);
  cast_f32_bf16<<<(C * C / 4 + 255) / 256, 256, 0, stream>>>(Wr, wrb, C * C / 4);

  gemm_proj_k<<<(NN / 16 + 3) / 4, 256, 0, stream>>>(xb, wpb, bp, h);

  hist_k<<<NE / 256, 256, 0, stream>>>(edst, deg);
  const int nb = (NN + 1023) / 1024;   // 98
  scan_block_k<<<nb, 1024, 0, stream>>>(deg, start, bsum, NN);
  scan_block_k<<<1, 1024, 0, stream>>>(bsum, bsum, nullptr, nb);
  scan_add_k<<<nb, 1024, 0, stream>>>(start, bsum, cursor, NN);
  reorder_k<<<NE / 256, 256, 0, stream>>>(esrc, edst, cursor, ssrc);

  aggregate_k<<<(NN + 3) / 4, 256, 0, stream>>>(h, ssrc, start, deg, aggb);

  gemm_out_k<<<(NN / 16 + 3) / 4, 256, 0, stream>>>(aggb, xb, wlb, wrb, bl, gamma, beta, out);
}

// Round 3
// 318.038 us; speedup vs baseline: 1.2847x; 1.2847x over previous
//
#include <hip/hip_runtime.h>
#include <stdint.h>

#define NN 100000
#define NE 1600000
#define C  128
#define NB 782          // buckets of 128 nodes: 782*128 = 100096 >= NN
#define CAP 4096        // phase-2 LDS capacity per bucket (mean 2048, sigma ~45)

typedef __attribute__((ext_vector_type(8))) short short8;
typedef __attribute__((ext_vector_type(4))) float f32x4;

__device__ __forceinline__ float bf2f(uint16_t u) {
  union { uint32_t u; float f; } v; v.u = ((uint32_t)u) << 16; return v.f;
}
__device__ __forceinline__ uint16_t f2bf(float f) {
  union { float f; uint32_t u; } v; v.f = f;
  uint32_t r = v.u + 0x7fffu + ((v.u >> 16) & 1u);   // RNE
  return (uint16_t)(r >> 16);
}

// ---------------- cast f32 -> bf16, 4 elems/thread ----------------
__global__ __launch_bounds__(256) void cast_f32_bf16(
    const float* __restrict__ src, uint16_t* __restrict__ dst, int n4)
{
  int i = blockIdx.x * 256 + threadIdx.x;
  if (i < n4) {
    float4 v = ((const float4*)src)[i];
    uint2 p;
    p.x = (uint32_t)f2bf(v.x) | ((uint32_t)f2bf(v.y) << 16);
    p.y = (uint32_t)f2bf(v.z) | ((uint32_t)f2bf(v.w) << 16);
    ((uint2*)dst)[i] = p;
  }
}

// ---------------- GEMM1: h = relu(x @ Wp^T + bp), bf16 MFMA ----------------
__global__ __launch_bounds__(256) void gemm_proj_k(
    const uint16_t* __restrict__ xb, const uint16_t* __restrict__ wpb,
    const float* __restrict__ bias, uint16_t* __restrict__ h)
{
  const int wid = (blockIdx.x * 256 + threadIdx.x) >> 6;
  const int tile_m = wid * 16;
  if (tile_m >= NN) return;
  const int lane = threadIdx.x & 63;
  const int r16 = lane & 15, g = lane >> 4;

  short8 a[4];
  const uint16_t* ap = xb + (size_t)(tile_m + r16) * C + g * 8;
#pragma unroll
  for (int kk = 0; kk < 4; ++kk) a[kk] = *(const short8*)(ap + kk * 32);

#pragma unroll
  for (int nt = 0; nt < 8; ++nt) {
    f32x4 acc = {0.f, 0.f, 0.f, 0.f};
    const uint16_t* bpp = wpb + (size_t)(nt * 16 + r16) * C + g * 8;
#pragma unroll
    for (int kk = 0; kk < 4; ++kk) {
      short8 b = *(const short8*)(bpp + kk * 32);
      acc = __builtin_amdgcn_mfma_f32_16x16x32_bf16(a[kk], b, acc, 0, 0, 0);
    }
    const int col = nt * 16 + r16;
    const float bv = bias[col];
#pragma unroll
    for (int r = 0; r < 4; ++r) {
      int row = tile_m + g * 4 + r;          // C/D: col=lane&15, row=(lane>>4)*4+r
      float v = acc[r] + bv;
      v = v > 0.f ? v : 0.f;
      h[(size_t)row * C + col] = f2bf(v);
    }
  }
}

// ---------------- histogram of dst (per-node degree) ----------------
__global__ __launch_bounds__(256) void hist_k(
    const int* __restrict__ dst, int* __restrict__ deg)
{
  int e = blockIdx.x * 256 + threadIdx.x;   // grid == NE exactly
  atomicAdd(&deg[dst[e]], 1);
}

// ---------------- 3-phase exclusive scan ----------------
__global__ __launch_bounds__(1024) void scan_block_k(
    const int* __restrict__ in, int* __restrict__ out, int* __restrict__ bsum, int n)
{
  __shared__ int sm[1024];
  int t = threadIdx.x;
  int i = blockIdx.x * 1024 + t;
  int v = (i < n) ? in[i] : 0;
  sm[t] = v;
  __syncthreads();
  for (int off = 1; off < 1024; off <<= 1) {
    int x = (t >= off) ? sm[t - off] : 0;
    __syncthreads();
    sm[t] += x;
    __syncthreads();
  }
  if (i < n) out[i] = sm[t] - v;            // exclusive within block
  if (t == 1023 && bsum) bsum[blockIdx.x] = sm[t];
}

__global__ __launch_bounds__(1024) void scan_add_k(
    int* __restrict__ start, const int* __restrict__ bsum, int n)
{
  int i = blockIdx.x * 1024 + threadIdx.x;
  if (i < n) start[i] += bsum[blockIdx.x];
}

// gcur[b] = CSR offset of first node of bucket b
__global__ __launch_bounds__(1024) void init_gcur_k(
    const int* __restrict__ start, int* __restrict__ gcur)
{
  int b = threadIdx.x;
  if (b < NB) gcur[b] = start[b * 128 < NN ? b * 128 : NN - 1];
}

// ---------------- phase 1: bucket edges by dst>>7 with per-block runs -------
// 250 blocks x 6400 edges. Packed value: (local_dst<<17)|src  (7+17=24 bits)
__global__ __launch_bounds__(256) void phase1_k(
    const int* __restrict__ esrc, const int* __restrict__ edst,
    int* __restrict__ gcur, uint32_t* __restrict__ ebuf)
{
  __shared__ int bh[NB];     // per-block bucket histogram
  __shared__ int gb[NB];     // reserved global base per bucket
  const int t = threadIdx.x;
  const int base = blockIdx.x * 6400;

  for (int b = t; b < NB; b += 256) bh[b] = 0;
  __syncthreads();

#pragma unroll
  for (int i = 0; i < 25; ++i) {
    int e = base + i * 256 + t;
    atomicAdd(&bh[edst[e] >> 7], 1);
  }
  __syncthreads();

  for (int b = t; b < NB; b += 256) {
    int c = bh[b];
    gb[b] = c ? atomicAdd(&gcur[b], c) : 0;
    bh[b] = 0;               // reuse as local cursor
  }
  __syncthreads();

#pragma unroll
  for (int i = 0; i < 25; ++i) {
    int e = base + i * 256 + t;
    int d = edst[e];
    int s = esrc[e];
    int b = d >> 7;
    int o = atomicAdd(&bh[b], 1);
    ebuf[gb[b] + o] = ((uint32_t)(d & 127) << 17) | (uint32_t)s;
  }
}

// ---------------- phase 2: per-bucket LDS counting-scatter, coalesced out ---
__global__ __launch_bounds__(256) void phase2_k(
    const uint32_t* __restrict__ ebuf, const int* __restrict__ start,
    int* __restrict__ ssrc)
{
  __shared__ int lout[CAP];
  __shared__ int sstart[128];
  __shared__ int lcur[128];
  const int b = blockIdx.x;
  const int t = threadIdx.x;
  const int n0 = b * 128;
  const int nn = (NN - n0 < 128) ? (NN - n0) : 128;

  if (t < nn) { sstart[t] = start[n0 + t]; lcur[t] = 0; }
  __syncthreads();
  const int ebase = sstart[0];
  const int eend = (b == NB - 1) ? NE : start[n0 + 128];
  const int count = eend - ebase;

  if (count <= CAP) {
    for (int i = t; i < count; i += 256) {
      uint32_t v = ebuf[ebase + i];
      int ld = v >> 17;
      int s  = (int)(v & 0x1FFFFu);
      int o  = atomicAdd(&lcur[ld], 1);
      lout[sstart[ld] - ebase + o] = s;
    }
    __syncthreads();
    for (int i = t; i < count; i += 256) ssrc[ebase + i] = lout[i];
  } else {
    // never expected for this input; correctness-preserving fallback
    for (int i = t; i < count; i += 256) {
      uint32_t v = ebuf[ebase + i];
      int ld = v >> 17;
      int s  = (int)(v & 0x1FFFFu);
      int o  = atomicAdd(&lcur[ld], 1);
      ssrc[sstart[ld] + o] = s;
    }
  }
}

// ---------------- atomic-free aggregation: 1 wave per node ----------------
__global__ __launch_bounds__(256) void aggregate_k(
    const uint16_t* __restrict__ h, const int* __restrict__ ssrc,
    const int* __restrict__ start, const int* __restrict__ deg,
    uint16_t* __restrict__ agg)
{
  int wid = (blockIdx.x * 256 + threadIdx.x) >> 6;
  if (wid >= NN) return;
  int lane = threadIdx.x & 63;
  int s0 = start[wid];
  int cnt = deg[wid];
  float a0 = 0.f, a1 = 0.f, b0 = 0.f, b1 = 0.f;
  int j = 0;
  for (; j + 2 <= cnt; j += 2) {            // unroll-2 for load ILP
    int sA = ssrc[s0 + j], sB = ssrc[s0 + j + 1];
    uint32_t vA = *(const uint32_t*)(h + (size_t)sA * C + lane * 2);
    uint32_t vB = *(const uint32_t*)(h + (size_t)sB * C + lane * 2);
    a0 += bf2f((uint16_t)vA); a1 += bf2f((uint16_t)(vA >> 16));
    b0 += bf2f((uint16_t)vB); b1 += bf2f((uint16_t)(vB >> 16));
  }
  if (j < cnt) {
    int sA = ssrc[s0 + j];
    uint32_t vA = *(const uint32_t*)(h + (size_t)sA * C + lane * 2);
    a0 += bf2f((uint16_t)vA); a1 += bf2f((uint16_t)(vA >> 16));
  }
  a0 += b0; a1 += b1;
  uint32_t p = (uint32_t)f2bf(a0) | ((uint32_t)f2bf(a1) << 16);
  *(uint32_t*)(agg + (size_t)wid * C + lane * 2) = p;
}

// ---------------- GEMM2 + LayerNorm fused ----------------
__global__ __launch_bounds__(256) void gemm_out_k(
    const uint16_t* __restrict__ aggb, const uint16_t* __restrict__ xb,
    const uint16_t* __restrict__ wlb, const uint16_t* __restrict__ wrb,
    const float* __restrict__ bl, const float* __restrict__ gamma,
    const float* __restrict__ beta, float* __restrict__ out)
{
  const int wid = (blockIdx.x * 256 + threadIdx.x) >> 6;
  const int tile_m = wid * 16;
  if (tile_m >= NN) return;
  const int lane = threadIdx.x & 63;
  const int r16 = lane & 15, g = lane >> 4;

  short8 a0[4], a1[4];
  const uint16_t* p0 = aggb + (size_t)(tile_m + r16) * C + g * 8;
  const uint16_t* p1 = xb   + (size_t)(tile_m + r16) * C + g * 8;
#pragma unroll
  for (int kk = 0; kk < 4; ++kk) {
    a0[kk] = *(const short8*)(p0 + kk * 32);
    a1[kk] = *(const short8*)(p1 + kk * 32);
  }

  f32x4 acc[8];
#pragma unroll
  for (int nt = 0; nt < 8; ++nt) {
    f32x4 c = {0.f, 0.f, 0.f, 0.f};
    const uint16_t* bpl = wlb + (size_t)(nt * 16 + r16) * C + g * 8;
    const uint16_t* bpr = wrb + (size_t)(nt * 16 + r16) * C + g * 8;
#pragma unroll
    for (int kk = 0; kk < 4; ++kk)
      c = __builtin_amdgcn_mfma_f32_16x16x32_bf16(a0[kk], *(const short8*)(bpl + kk * 32), c, 0, 0, 0);
#pragma unroll
    for (int kk = 0; kk < 4; ++kk)
      c = __builtin_amdgcn_mfma_f32_16x16x32_bf16(a1[kk], *(const short8*)(bpr + kk * 32), c, 0, 0, 0);
    const float bv = bl[nt * 16 + r16];
#pragma unroll
    for (int r = 0; r < 4; ++r) c[r] += bv;
    acc[nt] = c;
  }

  // LayerNorm: each row lives in one 16-lane group -> shfl_xor 1,2,4,8
  float s1[4], s2[4];
#pragma unroll
  for (int r = 0; r < 4; ++r) { s1[r] = 0.f; s2[r] = 0.f; }
#pragma unroll
  for (int nt = 0; nt < 8; ++nt)
#pragma unroll
    for (int r = 0; r < 4; ++r) { float v = acc[nt][r]; s1[r] += v; s2[r] += v * v; }
#pragma unroll
  for (int m = 1; m <= 8; m <<= 1) {
#pragma unroll
    for (int r = 0; r < 4; ++r) {
      s1[r] += __shfl_xor(s1[r], m, 64);
      s2[r] += __shfl_xor(s2[r], m, 64);
    }
  }
  float mean[4], rstd[4];
#pragma unroll
  for (int r = 0; r < 4; ++r) {
    mean[r] = s1[r] * (1.f / C);
    float var = s2[r] * (1.f / C) - mean[r] * mean[r];
    rstd[r] = rsqrtf(var + 1e-5f);
  }
#pragma unroll
  for (int nt = 0; nt < 8; ++nt) {
    const int col = nt * 16 + r16;
    const float gmv = gamma[col], btv = beta[col];
#pragma unroll
    for (int r = 0; r < 4; ++r) {
      int row = tile_m + g * 4 + r;
      out[(size_t)row * C + col] = (acc[nt][r] - mean[r]) * rstd[r] * gmv + btv;
    }
  }
}

// ---------------- launch ----------------
extern "C" void kernel_launch(void* const* d_in, const int* in_sizes, int n_in,
                              void* d_out, int out_size, void* d_ws, size_t ws_size,
                              hipStream_t stream)
{
  const float* x        = (const float*)d_in[0];
  const int* ei         = (const int*)d_in[1];     // int32 from harness
  const float* Wp       = (const float*)d_in[2];
  const float* bp       = (const float*)d_in[3];
  const float* Wl       = (const float*)d_in[4];
  const float* bl       = (const float*)d_in[5];
  const float* Wr       = (const float*)d_in[6];
  const float* gamma    = (const float*)d_in[7];
  const float* beta     = (const float*)d_in[8];
  float* out            = (float*)d_out;

  char* ws = (char*)d_ws;
  // ws layout (bytes), all 16B-aligned; total ~84.5 MB (unchanged)
  uint16_t* xb   = (uint16_t*)(ws + 0);          // 25,600,000  x as bf16
  uint16_t* h    = (uint16_t*)(ws + 25600000);   // 25,600,000  relu(proj) bf16
  uint16_t* aggb = (uint16_t*)(ws + 51200000);   // 25,600,000  agg bf16
  uint32_t* ebuf = (uint32_t*)(ws + 51200000);   // 6,400,000  ALIASES aggb (dead before aggb written)
  uint16_t* wpb  = (uint16_t*)(ws + 76800000);   // 32,768
  uint16_t* wlb  = (uint16_t*)(ws + 76832768);   // 32,768
  uint16_t* wrb  = (uint16_t*)(ws + 76865536);   // 32,768
  int* deg       = (int*)(ws + 76898304);        // 400,000
  int* start     = (int*)(ws + 77298304);        // 400,000
  int* gcur      = (int*)(ws + 77698304);        // 3,128 (NB)
  int* bsum      = (int*)(ws + 78098304);        // 4,096
  int* ssrc      = (int*)(ws + 78102400);        // 6,400,000

  const int* esrc = ei;        // edge_index[0]
  const int* edst = ei + NE;   // edge_index[1]

  hipMemsetAsync(deg, 0, NN * sizeof(int), stream);

  cast_f32_bf16<<<(NN * C / 4 + 255) / 256, 256, 0, stream>>>(x, xb, NN * C / 4);
  cast_f32_bf16<<<(C * C / 4 + 255) / 256, 256, 0, stream>>>(Wp, wpb, C * C / 4);
  cast_f32_bf16<<<(C * C / 4 + 255) / 256, 256, 0, stream>>>(Wl, wlb, C * C / 4);
  cast_f32_bf16<<<(C * C / 4 + 255) / 256, 256, 0, stream>>>(Wr, wrb, C * C / 4);

  gemm_proj_k<<<(NN / 16 + 3) / 4, 256, 0, stream>>>(xb, wpb, bp, h);

  hist_k<<<NE / 256, 256, 0, stream>>>(edst, deg);
  const int nb = (NN + 1023) / 1024;   // 98
  scan_block_k<<<nb, 1024, 0, stream>>>(deg, start, bsum, NN);
  scan_block_k<<<1, 1024, 0, stream>>>(bsum, bsum, nullptr, nb);
  scan_add_k<<<nb, 1024, 0, stream>>>(start, bsum, NN);
  init_gcur_k<<<1, 1024, 0, stream>>>(start, gcur);

  phase1_k<<<250, 256, 0, stream>>>(esrc, edst, gcur, ebuf);
  phase2_k<<<NB, 256, 0, stream>>>(ebuf, start, ssrc);

  aggregate_k<<<(NN + 3) / 4, 256, 0, stream>>>(h, ssrc, start, deg, aggb);

  gemm_out_k<<<(NN / 16 + 3) / 4, 256, 0, stream>>>(aggb, xb, wlb, wrb, bl, gamma, beta, out);
}

// Round 4
// 206.395 us; speedup vs baseline: 1.9796x; 1.5409x over previous
//
#include <hip/hip_runtime.h>
#include <stdint.h>

#define NN 100000
#define NE 1600000
#define C  128
#define NB 782          // buckets of 128 dst nodes: 782*128 = 100096 >= NN
#define CAP 4096        // per-bucket edge capacity (mean 2048, sigma ~45 -> 45-sigma headroom)
#define SB_SHIFT 13     // src coarse-slice shift: 16 slices of 8192 nodes (2 MB of h)

typedef __attribute__((ext_vector_type(8))) short short8;
typedef __attribute__((ext_vector_type(4))) float f32x4;

__device__ __forceinline__ float bf2f(uint16_t u) {
  union { uint32_t u; float f; } v; v.u = ((uint32_t)u) << 16; return v.f;
}
__device__ __forceinline__ uint16_t f2bf(float f) {
  union { float f; uint32_t u; } v; v.f = f;
  uint32_t r = v.u + 0x7fffu + ((v.u >> 16) & 1u);   // RNE
  return (uint16_t)(r >> 16);
}

// ---------------- cast the 3 weight matrices in one dispatch ----------------
__global__ __launch_bounds__(256) void cast3_k(
    const float* __restrict__ a, const float* __restrict__ b, const float* __restrict__ c,
    uint16_t* __restrict__ oa, uint16_t* __restrict__ ob, uint16_t* __restrict__ oc)
{
  int i = blockIdx.x * 256 + threadIdx.x;     // 3 * 4096 float4-groups
  int which = i >> 12, j = i & 4095;
  const float* s = which == 0 ? a : (which == 1 ? b : c);
  uint16_t* d    = which == 0 ? oa : (which == 1 ? ob : oc);
  float4 v = ((const float4*)s)[j];
  uint2 p;
  p.x = (uint32_t)f2bf(v.x) | ((uint32_t)f2bf(v.y) << 16);
  p.y = (uint32_t)f2bf(v.z) | ((uint32_t)f2bf(v.w) << 16);
  ((uint2*)d)[j] = p;
}

// ------- GEMM1 (+ fused x->bf16 cast): h = relu(x @ Wp^T + bp) --------------
__global__ __launch_bounds__(256) void gemm_proj_k(
    const float* __restrict__ x, const uint16_t* __restrict__ wpb,
    const float* __restrict__ bias, uint16_t* __restrict__ h,
    uint16_t* __restrict__ xb)
{
  const int wid = (blockIdx.x * 256 + threadIdx.x) >> 6;
  const int tile_m = wid * 16;
  if (tile_m >= NN) return;
  const int lane = threadIdx.x & 63;
  const int r16 = lane & 15, g = lane >> 4;

  short8 a[4];
  const float* xp = x + (size_t)(tile_m + r16) * C + g * 8;
  uint16_t* xbp = xb + (size_t)(tile_m + r16) * C + g * 8;
#pragma unroll
  for (int kk = 0; kk < 4; ++kk) {
    float4 u = *(const float4*)(xp + kk * 32);
    float4 w = *(const float4*)(xp + kk * 32 + 4);
    short8 av;
    av[0] = (short)f2bf(u.x); av[1] = (short)f2bf(u.y);
    av[2] = (short)f2bf(u.z); av[3] = (short)f2bf(u.w);
    av[4] = (short)f2bf(w.x); av[5] = (short)f2bf(w.y);
    av[6] = (short)f2bf(w.z); av[7] = (short)f2bf(w.w);
    a[kk] = av;
    *(short8*)(xbp + kk * 32) = av;          // xb for gemm_out root branch
  }

#pragma unroll
  for (int nt = 0; nt < 8; ++nt) {
    f32x4 acc = {0.f, 0.f, 0.f, 0.f};
    const uint16_t* bpp = wpb + (size_t)(nt * 16 + r16) * C + g * 8;
#pragma unroll
    for (int kk = 0; kk < 4; ++kk) {
      short8 b = *(const short8*)(bpp + kk * 32);
      acc = __builtin_amdgcn_mfma_f32_16x16x32_bf16(a[kk], b, acc, 0, 0, 0);
    }
    const int col = nt * 16 + r16;
    const float bv = bias[col];
#pragma unroll
    for (int r = 0; r < 4; ++r) {
      int row = tile_m + g * 4 + r;          // C/D: col=lane&15, row=(lane>>4)*4+r
      float v = acc[r] + bv;
      v = v > 0.f ? v : 0.f;
      h[(size_t)row * C + col] = f2bf(v);
    }
  }
}

// ------- phase 1: bucket edges by dst>>7 into fixed-capacity regions --------
// 250 blocks x 6400 edges; also produces per-bucket counts (gcnt).
__global__ __launch_bounds__(256) void phase1_k(
    const int* __restrict__ esrc, const int* __restrict__ edst,
    int* __restrict__ gcnt, uint32_t* __restrict__ ebuf)
{
  __shared__ int bh[NB];     // per-block bucket histogram / local cursor
  __shared__ int gb[NB];     // reserved base inside bucket region
  const int t = threadIdx.x;
  const int base = blockIdx.x * 6400;

  for (int i = t; i < NB; i += 256) bh[i] = 0;

  const int4* ed4 = (const int4*)(edst + base);
  const int4* es4 = (const int4*)(esrc + base);
  int4 dv[6], sv[6];
#pragma unroll
  for (int i = 0; i < 6; ++i) { dv[i] = ed4[i * 256 + t]; sv[i] = es4[i * 256 + t]; }
  const int dlast = edst[base + 6144 + t];
  const int slast = esrc[base + 6144 + t];
  __syncthreads();

#pragma unroll
  for (int i = 0; i < 6; ++i) {
    atomicAdd(&bh[dv[i].x >> 7], 1); atomicAdd(&bh[dv[i].y >> 7], 1);
    atomicAdd(&bh[dv[i].z >> 7], 1); atomicAdd(&bh[dv[i].w >> 7], 1);
  }
  atomicAdd(&bh[dlast >> 7], 1);
  __syncthreads();

  for (int i = t; i < NB; i += 256) {
    int c = bh[i];
    gb[i] = c ? atomicAdd(&gcnt[i], c) : 0;
    bh[i] = 0;               // reuse as local cursor
  }
  __syncthreads();

#define P1_SCATTER(d, s) do { \
    int bb = (d) >> 7; \
    int o = atomicAdd(&bh[bb], 1); \
    int pos = gb[bb] + o; \
    if (pos < CAP) ebuf[(size_t)bb * CAP + pos] = ((uint32_t)((d) & 127) << 17) | (uint32_t)(s); \
  } while (0)

#pragma unroll
  for (int i = 0; i < 6; ++i) {
    P1_SCATTER(dv[i].x, sv[i].x); P1_SCATTER(dv[i].y, sv[i].y);
    P1_SCATTER(dv[i].z, sv[i].z); P1_SCATTER(dv[i].w, sv[i].w);
  }
  P1_SCATTER(dlast, slast);
#undef P1_SCATTER
}

// ---------------- exclusive scan (1 block) over NB bucket counts ------------
__global__ __launch_bounds__(1024) void scan_block_k(
    const int* __restrict__ in, int* __restrict__ out, int n)
{
  __shared__ int sm[1024];
  int t = threadIdx.x;
  int v = (t < n) ? in[t] : 0;
  sm[t] = v;
  __syncthreads();
  for (int off = 1; off < 1024; off <<= 1) {
    int x = (t >= off) ? sm[t - off] : 0;
    __syncthreads();
    sm[t] += x;
    __syncthreads();
  }
  if (t < n) out[t] = sm[t] - v;            // exclusive
}

// ------- phase 2: per-bucket LDS sort by (local_dst, src>>13) ---------------
// Emits CSR: ssrc (coalesced), per-node start/deg. Per-node lists are ordered
// by coarse src slice -> aggregate gathers sweep h in ~2 MB windows.
__global__ __launch_bounds__(256) void phase2_k(
    const uint32_t* __restrict__ ebuf, const int* __restrict__ gcnt,
    const int* __restrict__ gbase, int* __restrict__ ssrc,
    int* __restrict__ start, int* __restrict__ deg)
{
  __shared__ uint32_t raw[CAP];
  __shared__ int lout[CAP];
  __shared__ int cnt2[128 * 16];
  __shared__ int nd[128];
  const int b = blockIdx.x, t = threadIdx.x;
  const int n0 = b * 128;
  int cnt = gcnt[b]; if (cnt > CAP) cnt = CAP;
  const int base = gbase[b];

  for (int i = t; i < 128 * 16; i += 256) cnt2[i] = 0;
  __syncthreads();
  for (int i = t; i < cnt; i += 256) {
    uint32_t v = ebuf[(size_t)b * CAP + i];
    raw[i] = v;
    atomicAdd(&cnt2[(v >> 17) * 16 + ((v & 0x1FFFFu) >> SB_SHIFT)], 1);
  }
  __syncthreads();

  int deg_t = 0;
  if (t < 128) {
#pragma unroll
    for (int i = 0; i < 16; ++i) deg_t += cnt2[t * 16 + i];
    nd[t] = deg_t;
  }
  __syncthreads();
  // Hillis-Steele inclusive scan over nd[0..127]
  for (int off = 1; off < 128; off <<= 1) {
    int v = 0;
    if (t < 128 && t >= off) v = nd[t - off];
    __syncthreads();
    if (t < 128) nd[t] += v;
    __syncthreads();
  }
  if (t < 128) {
    int pref = nd[t] - deg_t;               // exclusive
    if (n0 + t < NN) { start[n0 + t] = base + pref; deg[n0 + t] = deg_t; }
    int run = pref;
#pragma unroll
    for (int i = 0; i < 16; ++i) { int c = cnt2[t * 16 + i]; cnt2[t * 16 + i] = run; run += c; }
  }
  __syncthreads();
  for (int i = t; i < cnt; i += 256) {
    uint32_t v = raw[i];
    int o = atomicAdd(&cnt2[(v >> 17) * 16 + ((v & 0x1FFFFu) >> SB_SHIFT)], 1);
    lout[o] = (int)(v & 0x1FFFFu);
  }
  __syncthreads();
  for (int i = t; i < cnt; i += 256) ssrc[base + i] = lout[i];
}

// ------- aggregation: 1 wave per node, half-wave edge pairs, 8 in flight ----
__global__ __launch_bounds__(256) void aggregate_k(
    const uint16_t* __restrict__ h, const int* __restrict__ ssrc,
    const int* __restrict__ start, const int* __restrict__ deg,
    uint16_t* __restrict__ agg)
{
  const int wid = (blockIdx.x * 256 + threadIdx.x) >> 6;
  if (wid >= NN) return;
  const int lane = threadIdx.x & 63;
  const int half = lane >> 5;          // 0: even edges, 1: odd edges
  const int l32 = lane & 31;           // channels l32*4 .. l32*4+3
  const int s0 = start[wid];
  const int cnt = deg[wid];
  const size_t choff = (size_t)l32 * 4;
  float a0 = 0.f, a1 = 0.f, a2 = 0.f, a3 = 0.f;

#define ACC(v) do { \
    a0 += bf2f((uint16_t)(v).x); a1 += bf2f((uint16_t)((v).x >> 16)); \
    a2 += bf2f((uint16_t)(v).y); a3 += bf2f((uint16_t)((v).y >> 16)); \
  } while (0)

  int j = 0;
  for (; j + 8 <= cnt; j += 8) {       // 8 edges in flight (4 uint2 loads/wave)
    int e0 = ssrc[s0 + j + 0 + half];
    int e1 = ssrc[s0 + j + 2 + half];
    int e2 = ssrc[s0 + j + 4 + half];
    int e3 = ssrc[s0 + j + 6 + half];
    uint2 v0 = *(const uint2*)(h + (size_t)e0 * C + choff);
    uint2 v1 = *(const uint2*)(h + (size_t)e1 * C + choff);
    uint2 v2 = *(const uint2*)(h + (size_t)e2 * C + choff);
    uint2 v3 = *(const uint2*)(h + (size_t)e3 * C + choff);
    ACC(v0); ACC(v1); ACC(v2); ACC(v3);
  }
  for (; j + 2 <= cnt; j += 2) {
    int e = ssrc[s0 + j + half];
    uint2 v = *(const uint2*)(h + (size_t)e * C + choff);
    ACC(v);
  }
  if (j < cnt && half == 0) {          // odd leftover: lanes 0-31 only
    int e = ssrc[s0 + j];
    uint2 v = *(const uint2*)(h + (size_t)e * C + choff);
    ACC(v);
  }
#undef ACC

  a0 += __shfl_xor(a0, 32, 64);
  a1 += __shfl_xor(a1, 32, 64);
  a2 += __shfl_xor(a2, 32, 64);
  a3 += __shfl_xor(a3, 32, 64);
  if (half == 0) {
    uint2 p;
    p.x = (uint32_t)f2bf(a0) | ((uint32_t)f2bf(a1) << 16);
    p.y = (uint32_t)f2bf(a2) | ((uint32_t)f2bf(a3) << 16);
    *(uint2*)(agg + (size_t)wid * C + choff) = p;
  }
}

// ---------------- GEMM2 + LayerNorm fused ----------------
__global__ __launch_bounds__(256) void gemm_out_k(
    const uint16_t* __restrict__ aggb, const uint16_t* __restrict__ xb,
    const uint16_t* __restrict__ wlb, const uint16_t* __restrict__ wrb,
    const float* __restrict__ bl, const float* __restrict__ gamma,
    const float* __restrict__ beta, float* __restrict__ out)
{
  const int wid = (blockIdx.x * 256 + threadIdx.x) >> 6;
  const int tile_m = wid * 16;
  if (tile_m >= NN) return;
  const int lane = threadIdx.x & 63;
  const int r16 = lane & 15, g = lane >> 4;

  short8 a0[4], a1[4];
  const uint16_t* p0 = aggb + (size_t)(tile_m + r16) * C + g * 8;
  const uint16_t* p1 = xb   + (size_t)(tile_m + r16) * C + g * 8;
#pragma unroll
  for (int kk = 0; kk < 4; ++kk) {
    a0[kk] = *(const short8*)(p0 + kk * 32);
    a1[kk] = *(const short8*)(p1 + kk * 32);
  }

  f32x4 acc[8];
#pragma unroll
  for (int nt = 0; nt < 8; ++nt) {
    f32x4 c = {0.f, 0.f, 0.f, 0.f};
    const uint16_t* bpl = wlb + (size_t)(nt * 16 + r16) * C + g * 8;
    const uint16_t* bpr = wrb + (size_t)(nt * 16 + r16) * C + g * 8;
#pragma unroll
    for (int kk = 0; kk < 4; ++kk)
      c = __builtin_amdgcn_mfma_f32_16x16x32_bf16(a0[kk], *(const short8*)(bpl + kk * 32), c, 0, 0, 0);
#pragma unroll
    for (int kk = 0; kk < 4; ++kk)
      c = __builtin_amdgcn_mfma_f32_16x16x32_bf16(a1[kk], *(const short8*)(bpr + kk * 32), c, 0, 0, 0);
    const float bv = bl[nt * 16 + r16];
#pragma unroll
    for (int r = 0; r < 4; ++r) c[r] += bv;
    acc[nt] = c;
  }

  // LayerNorm: each row lives in one 16-lane group -> shfl_xor 1,2,4,8
  float s1[4], s2[4];
#pragma unroll
  for (int r = 0; r < 4; ++r) { s1[r] = 0.f; s2[r] = 0.f; }
#pragma unroll
  for (int nt = 0; nt < 8; ++nt)
#pragma unroll
    for (int r = 0; r < 4; ++r) { float v = acc[nt][r]; s1[r] += v; s2[r] += v * v; }
#pragma unroll
  for (int m = 1; m <= 8; m <<= 1) {
#pragma unroll
    for (int r = 0; r < 4; ++r) {
      s1[r] += __shfl_xor(s1[r], m, 64);
      s2[r] += __shfl_xor(s2[r], m, 64);
    }
  }
  float mean[4], rstd[4];
#pragma unroll
  for (int r = 0; r < 4; ++r) {
    mean[r] = s1[r] * (1.f / C);
    float var = s2[r] * (1.f / C) - mean[r] * mean[r];
    rstd[r] = rsqrtf(var + 1e-5f);
  }
#pragma unroll
  for (int nt = 0; nt < 8; ++nt) {
    const int col = nt * 16 + r16;
    const float gmv = gamma[col], btv = beta[col];
#pragma unroll
    for (int r = 0; r < 4; ++r) {
      int row = tile_m + g * 4 + r;
      out[(size_t)row * C + col] = (acc[nt][r] - mean[r]) * rstd[r] * gmv + btv;
    }
  }
}

// ---------------- launch ----------------
extern "C" void kernel_launch(void* const* d_in, const int* in_sizes, int n_in,
                              void* d_out, int out_size, void* d_ws, size_t ws_size,
                              hipStream_t stream)
{
  const float* x        = (const float*)d_in[0];
  const int* ei         = (const int*)d_in[1];     // int32 from harness
  const float* Wp       = (const float*)d_in[2];
  const float* bp       = (const float*)d_in[3];
  const float* Wl       = (const float*)d_in[4];
  const float* bl       = (const float*)d_in[5];
  const float* Wr       = (const float*)d_in[6];
  const float* gamma    = (const float*)d_in[7];
  const float* beta     = (const float*)d_in[8];
  float* out            = (float*)d_out;

  char* ws = (char*)d_ws;
  uint16_t* xb   = (uint16_t*)(ws + 0);          // 25,600,000  x as bf16
  uint16_t* h    = (uint16_t*)(ws + 25600000);   // 25,600,000  relu(proj) bf16
  uint16_t* aggb = (uint16_t*)(ws + 51200000);   // 25,600,000  agg bf16
  uint32_t* ebuf = (uint32_t*)(ws + 51200000);   // 12,812,288  ALIASES aggb (dead before aggb written)
  uint16_t* wpb  = (uint16_t*)(ws + 76800000);   // 32,768
  uint16_t* wlb  = (uint16_t*)(ws + 76832768);   // 32,768
  uint16_t* wrb  = (uint16_t*)(ws + 76865536);   // 32,768
  int* deg       = (int*)(ws + 76898304);        // 400,000
  int* start     = (int*)(ws + 77298304);        // 400,000
  int* gcnt      = (int*)(ws + 77698304);        // 3,128
  int* gbase     = (int*)(ws + 77702400);        // 3,128
  int* ssrc      = (int*)(ws + 78102400);        // 6,400,000

  const int* esrc = ei;        // edge_index[0]
  const int* edst = ei + NE;   // edge_index[1]

  hipMemsetAsync(gcnt, 0, NB * sizeof(int), stream);

  cast3_k<<<48, 256, 0, stream>>>(Wp, Wl, Wr, wpb, wlb, wrb);
  gemm_proj_k<<<(NN / 16 + 3) / 4, 256, 0, stream>>>(x, wpb, bp, h, xb);

  phase1_k<<<250, 256, 0, stream>>>(esrc, edst, gcnt, ebuf);
  scan_block_k<<<1, 1024, 0, stream>>>(gcnt, gbase, NB);
  phase2_k<<<NB, 256, 0, stream>>>(ebuf, gcnt, gbase, ssrc, start, deg);

  aggregate_k<<<(NN + 3) / 4, 256, 0, stream>>>(h, ssrc, start, deg, aggb);

  gemm_out_k<<<(NN / 16 + 3) / 4, 256, 0, stream>>>(aggb, xb, wlb, wrb, bl, gamma, beta, out);
}

// Round 5
// 148.704 us; speedup vs baseline: 2.7476x; 1.3880x over previous
//
#include <hip/hip_runtime.h>
#include <stdint.h>

#define NN 100000
#define NE 1600000
#define C  128
#define NB 782          // buckets of 128 dst nodes: 782*128 = 100096 >= NN
#define CAP 4096        // per-bucket edge capacity (mean 2048, sigma ~45)
#define SB_SHIFT 13     // src coarse-slice shift for L2-friendly gather order
#define MB 782          // GEMM blocks: 128 rows each

typedef __attribute__((ext_vector_type(8))) short short8;
typedef __attribute__((ext_vector_type(4))) float f32x4;

__device__ __forceinline__ float bf2f(uint16_t u) {
  union { uint32_t u; float f; } v; v.u = ((uint32_t)u) << 16; return v.f;
}
__device__ __forceinline__ uint16_t f2bf(float f) {
  union { float f; uint32_t u; } v; v.f = f;
  uint32_t r = v.u + 0x7fffu + ((v.u >> 16) & 1u);   // RNE
  return (uint16_t)(r >> 16);
}

// ---------------- cast the 3 weight matrices in one dispatch ----------------
__global__ __launch_bounds__(256) void cast3_k(
    const float* __restrict__ a, const float* __restrict__ b, const float* __restrict__ c,
    uint16_t* __restrict__ oa, uint16_t* __restrict__ ob, uint16_t* __restrict__ oc)
{
  int i = blockIdx.x * 256 + threadIdx.x;     // 3 * 4096 float4-groups
  int which = i >> 12, j = i & 4095;
  const float* s = which == 0 ? a : (which == 1 ? b : c);
  uint16_t* d    = which == 0 ? oa : (which == 1 ? ob : oc);
  float4 v = ((const float4*)s)[j];
  uint2 p;
  p.x = (uint32_t)f2bf(v.x) | ((uint32_t)f2bf(v.y) << 16);
  p.y = (uint32_t)f2bf(v.z) | ((uint32_t)f2bf(v.w) << 16);
  ((uint2*)d)[j] = p;
}

// LDS weight tile: 16B chunk (c, k16) at byte c*256 + ((k16 ^ (c&15))<<4).
// Read of frag (c, kk, g) -> slot (kk*4+g)^(c&15): 4 rows/slot = baseline b128.

// ------- GEMM1 (+ fused x->bf16 cast): h = relu(x @ Wp^T + bp) --------------
// 512 thr = 8 waves x 16 rows = 128 rows/block; Wp staged in 32 KB LDS.
__global__ __launch_bounds__(512) void gemm_proj_k(
    const float* __restrict__ x, const uint16_t* __restrict__ wpb,
    const float* __restrict__ bias, uint16_t* __restrict__ h,
    uint16_t* __restrict__ xb)
{
  extern __shared__ uint8_t slds[];
  const int t = threadIdx.x;
#pragma unroll
  for (int q = 0; q < 4; ++q) {               // 2048 chunks of 16B
    int ci = q * 512 + t;
    int c = ci >> 4, k16 = ci & 15;
    *(short8*)(slds + c * 256 + ((k16 ^ (c & 15)) << 4)) =
        *(const short8*)(wpb + ci * 8);
  }
  __syncthreads();

  const int w = t >> 6, lane = t & 63;
  const int tile_m = blockIdx.x * 128 + w * 16;
  if (tile_m >= NN) return;
  const int r16 = lane & 15, g = lane >> 4;

  short8 a[4];
  const float* xp = x + (size_t)(tile_m + r16) * C + g * 8;
  uint16_t* xbp = xb + (size_t)(tile_m + r16) * C + g * 8;
#pragma unroll
  for (int kk = 0; kk < 4; ++kk) {
    float4 u = *(const float4*)(xp + kk * 32);
    float4 v = *(const float4*)(xp + kk * 32 + 4);
    short8 av;
    av[0] = (short)f2bf(u.x); av[1] = (short)f2bf(u.y);
    av[2] = (short)f2bf(u.z); av[3] = (short)f2bf(u.w);
    av[4] = (short)f2bf(v.x); av[5] = (short)f2bf(v.y);
    av[6] = (short)f2bf(v.z); av[7] = (short)f2bf(v.w);
    a[kk] = av;
    *(short8*)(xbp + kk * 32) = av;
  }

#pragma unroll
  for (int nt = 0; nt < 8; ++nt) {
    f32x4 acc = {0.f, 0.f, 0.f, 0.f};
    const int c = nt * 16 + r16;
    const uint8_t* rb = slds + c * 256;
#pragma unroll
    for (int kk = 0; kk < 4; ++kk) {
      short8 b = *(const short8*)(rb + ((((kk << 2) + g) ^ (c & 15)) << 4));
      acc = __builtin_amdgcn_mfma_f32_16x16x32_bf16(a[kk], b, acc, 0, 0, 0);
    }
    const float bv = bias[c];
#pragma unroll
    for (int r = 0; r < 4; ++r) {
      int row = tile_m + g * 4 + r;          // C/D: col=lane&15, row=(lane>>4)*4+r
      float v = acc[r] + bv;
      v = v > 0.f ? v : 0.f;
      h[(size_t)row * C + c] = f2bf(v);
    }
  }
}

// ------- phase 1: bucket edges by dst>>7 into fixed-capacity regions --------
__global__ __launch_bounds__(256) void phase1_k(
    const int* __restrict__ esrc, const int* __restrict__ edst,
    int* __restrict__ gcnt, uint32_t* __restrict__ ebuf)
{
  __shared__ int bh[NB];     // per-block bucket histogram / local cursor
  __shared__ int gb[NB];     // reserved base inside bucket region
  const int t = threadIdx.x;
  const int base = blockIdx.x * 6400;

  for (int i = t; i < NB; i += 256) bh[i] = 0;

  const int4* ed4 = (const int4*)(edst + base);
  const int4* es4 = (const int4*)(esrc + base);
  int4 dv[6], sv[6];
#pragma unroll
  for (int i = 0; i < 6; ++i) { dv[i] = ed4[i * 256 + t]; sv[i] = es4[i * 256 + t]; }
  const int dlast = edst[base + 6144 + t];
  const int slast = esrc[base + 6144 + t];
  __syncthreads();

#pragma unroll
  for (int i = 0; i < 6; ++i) {
    atomicAdd(&bh[dv[i].x >> 7], 1); atomicAdd(&bh[dv[i].y >> 7], 1);
    atomicAdd(&bh[dv[i].z >> 7], 1); atomicAdd(&bh[dv[i].w >> 7], 1);
  }
  atomicAdd(&bh[dlast >> 7], 1);
  __syncthreads();

  for (int i = t; i < NB; i += 256) {
    int c = bh[i];
    gb[i] = c ? atomicAdd(&gcnt[i], c) : 0;
    bh[i] = 0;               // reuse as local cursor
  }
  __syncthreads();

#define P1_SCATTER(d, s) do { \
    int bb = (d) >> 7; \
    int o = atomicAdd(&bh[bb], 1); \
    int pos = gb[bb] + o; \
    if (pos < CAP) ebuf[(size_t)bb * CAP + pos] = ((uint32_t)((d) & 127) << 17) | (uint32_t)(s); \
  } while (0)

#pragma unroll
  for (int i = 0; i < 6; ++i) {
    P1_SCATTER(dv[i].x, sv[i].x); P1_SCATTER(dv[i].y, sv[i].y);
    P1_SCATTER(dv[i].z, sv[i].z); P1_SCATTER(dv[i].w, sv[i].w);
  }
  P1_SCATTER(dlast, slast);
#undef P1_SCATTER
}

// ---------------- exclusive scan (1 block) over NB bucket counts ------------
__global__ __launch_bounds__(1024) void scan_block_k(
    const int* __restrict__ in, int* __restrict__ out, int n)
{
  __shared__ int sm[1024];
  int t = threadIdx.x;
  int v = (t < n) ? in[t] : 0;
  sm[t] = v;
  __syncthreads();
  for (int off = 1; off < 1024; off <<= 1) {
    int x = (t >= off) ? sm[t - off] : 0;
    __syncthreads();
    sm[t] += x;
    __syncthreads();
  }
  if (t < n) out[t] = sm[t] - v;            // exclusive
}

// ------- phase 2: per-bucket LDS sort by (local_dst, src>>13) ---------------
__global__ __launch_bounds__(256) void phase2_k(
    const uint32_t* __restrict__ ebuf, const int* __restrict__ gcnt,
    const int* __restrict__ gbase, int* __restrict__ ssrc,
    int* __restrict__ start, int* __restrict__ deg)
{
  __shared__ uint32_t raw[CAP];
  __shared__ int lout[CAP];
  __shared__ int cnt2[128 * 16];
  __shared__ int nd[128];
  const int b = blockIdx.x, t = threadIdx.x;
  const int n0 = b * 128;
  int cnt = gcnt[b]; if (cnt > CAP) cnt = CAP;
  const int base = gbase[b];

  for (int i = t; i < 128 * 16; i += 256) cnt2[i] = 0;
  __syncthreads();
  for (int i = t; i < cnt; i += 256) {
    uint32_t v = ebuf[(size_t)b * CAP + i];
    raw[i] = v;
    atomicAdd(&cnt2[(v >> 17) * 16 + ((v & 0x1FFFFu) >> SB_SHIFT)], 1);
  }
  __syncthreads();

  int deg_t = 0;
  if (t < 128) {
#pragma unroll
    for (int i = 0; i < 16; ++i) deg_t += cnt2[t * 16 + i];
    nd[t] = deg_t;
  }
  __syncthreads();
  for (int off = 1; off < 128; off <<= 1) {
    int v = 0;
    if (t < 128 && t >= off) v = nd[t - off];
    __syncthreads();
    if (t < 128) nd[t] += v;
    __syncthreads();
  }
  if (t < 128) {
    int pref = nd[t] - deg_t;               // exclusive
    if (n0 + t < NN) { start[n0 + t] = base + pref; deg[n0 + t] = deg_t; }
    int run = pref;
#pragma unroll
    for (int i = 0; i < 16; ++i) { int c = cnt2[t * 16 + i]; cnt2[t * 16 + i] = run; run += c; }
  }
  __syncthreads();
  for (int i = t; i < cnt; i += 256) {
    uint32_t v = raw[i];
    int o = atomicAdd(&cnt2[(v >> 17) * 16 + ((v & 0x1FFFFu) >> SB_SHIFT)], 1);
    lout[o] = (int)(v & 0x1FFFFu);
  }
  __syncthreads();
  for (int i = t; i < cnt; i += 256) ssrc[base + i] = lout[i];
}

// ------- aggregation: 1 wave per node, half-wave edge pairs, 8 in flight ----
__global__ __launch_bounds__(256) void aggregate_k(
    const uint16_t* __restrict__ h, const int* __restrict__ ssrc,
    const int* __restrict__ start, const int* __restrict__ deg,
    uint16_t* __restrict__ agg)
{
  const int wid = (blockIdx.x * 256 + threadIdx.x) >> 6;
  if (wid >= NN) return;
  const int lane = threadIdx.x & 63;
  const int half = lane >> 5;          // 0: even edges, 1: odd edges
  const int l32 = lane & 31;           // channels l32*4 .. l32*4+3
  const int s0 = start[wid];
  const int cnt = deg[wid];
  const size_t choff = (size_t)l32 * 4;
  float a0 = 0.f, a1 = 0.f, a2 = 0.f, a3 = 0.f;

#define ACC(v) do { \
    a0 += bf2f((uint16_t)(v).x); a1 += bf2f((uint16_t)((v).x >> 16)); \
    a2 += bf2f((uint16_t)(v).y); a3 += bf2f((uint16_t)((v).y >> 16)); \
  } while (0)

  int j = 0;
  for (; j + 8 <= cnt; j += 8) {       // 8 edges in flight (4 uint2 loads/wave)
    int e0 = ssrc[s0 + j + 0 + half];
    int e1 = ssrc[s0 + j + 2 + half];
    int e2 = ssrc[s0 + j + 4 + half];
    int e3 = ssrc[s0 + j + 6 + half];
    uint2 v0 = *(const uint2*)(h + (size_t)e0 * C + choff);
    uint2 v1 = *(const uint2*)(h + (size_t)e1 * C + choff);
    uint2 v2 = *(const uint2*)(h + (size_t)e2 * C + choff);
    uint2 v3 = *(const uint2*)(h + (size_t)e3 * C + choff);
    ACC(v0); ACC(v1); ACC(v2); ACC(v3);
  }
  for (; j + 2 <= cnt; j += 2) {
    int e = ssrc[s0 + j + half];
    uint2 v = *(const uint2*)(h + (size_t)e * C + choff);
    ACC(v);
  }
  if (j < cnt && half == 0) {          // odd leftover: lanes 0-31 only
    int e = ssrc[s0 + j];
    uint2 v = *(const uint2*)(h + (size_t)e * C + choff);
    ACC(v);
  }
#undef ACC

  a0 += __shfl_xor(a0, 32, 64);
  a1 += __shfl_xor(a1, 32, 64);
  a2 += __shfl_xor(a2, 32, 64);
  a3 += __shfl_xor(a3, 32, 64);
  if (half == 0) {
    uint2 p;
    p.x = (uint32_t)f2bf(a0) | ((uint32_t)f2bf(a1) << 16);
    p.y = (uint32_t)f2bf(a2) | ((uint32_t)f2bf(a3) << 16);
    *(uint2*)(agg + (size_t)wid * C + choff) = p;
  }
}

// ---------------- GEMM2 + LayerNorm fused; Wl+Wr staged in 64 KB LDS --------
// 512 thr = 8 waves x 16 rows = 128 rows/block.
__global__ __launch_bounds__(512) void gemm_out_k(
    const uint16_t* __restrict__ aggb, const uint16_t* __restrict__ xb,
    const uint16_t* __restrict__ wlb, const uint16_t* __restrict__ wrb,
    const float* __restrict__ bl, const float* __restrict__ gamma,
    const float* __restrict__ beta, float* __restrict__ out)
{
  extern __shared__ uint8_t slds[];
  const int t = threadIdx.x;
#pragma unroll
  for (int q = 0; q < 4; ++q) {               // Wl: 2048 chunks
    int ci = q * 512 + t;
    int c = ci >> 4, k16 = ci & 15;
    *(short8*)(slds + c * 256 + ((k16 ^ (c & 15)) << 4)) =
        *(const short8*)(wlb + ci * 8);
  }
#pragma unroll
  for (int q = 0; q < 4; ++q) {               // Wr: 2048 chunks at +32KB
    int ci = q * 512 + t;
    int c = ci >> 4, k16 = ci & 15;
    *(short8*)(slds + 32768 + c * 256 + ((k16 ^ (c & 15)) << 4)) =
        *(const short8*)(wrb + ci * 8);
  }
  __syncthreads();

  const int w = t >> 6, lane = t & 63;
  const int tile_m = blockIdx.x * 128 + w * 16;
  if (tile_m >= NN) return;
  const int r16 = lane & 15, g = lane >> 4;

  short8 a0[4], a1[4];
  const uint16_t* p0 = aggb + (size_t)(tile_m + r16) * C + g * 8;
  const uint16_t* p1 = xb   + (size_t)(tile_m + r16) * C + g * 8;
#pragma unroll
  for (int kk = 0; kk < 4; ++kk) {
    a0[kk] = *(const short8*)(p0 + kk * 32);
    a1[kk] = *(const short8*)(p1 + kk * 32);
  }

  f32x4 acc[8];
#pragma unroll
  for (int nt = 0; nt < 8; ++nt) {
    f32x4 c4 = {0.f, 0.f, 0.f, 0.f};
    const int c = nt * 16 + r16;
    const uint8_t* rbl = slds + c * 256;
    const uint8_t* rbr = slds + 32768 + c * 256;
#pragma unroll
    for (int kk = 0; kk < 4; ++kk) {
      short8 b = *(const short8*)(rbl + ((((kk << 2) + g) ^ (c & 15)) << 4));
      c4 = __builtin_amdgcn_mfma_f32_16x16x32_bf16(a0[kk], b, c4, 0, 0, 0);
    }
#pragma unroll
    for (int kk = 0; kk < 4; ++kk) {
      short8 b = *(const short8*)(rbr + ((((kk << 2) + g) ^ (c & 15)) << 4));
      c4 = __builtin_amdgcn_mfma_f32_16x16x32_bf16(a1[kk], b, c4, 0, 0, 0);
    }
    const float bv = bl[c];
#pragma unroll
    for (int r = 0; r < 4; ++r) c4[r] += bv;
    acc[nt] = c4;
  }

  // LayerNorm: each row lives in one 16-lane group -> shfl_xor 1,2,4,8
  float s1[4], s2[4];
#pragma unroll
  for (int r = 0; r < 4; ++r) { s1[r] = 0.f; s2[r] = 0.f; }
#pragma unroll
  for (int nt = 0; nt < 8; ++nt)
#pragma unroll
    for (int r = 0; r < 4; ++r) { float v = acc[nt][r]; s1[r] += v; s2[r] += v * v; }
#pragma unroll
  for (int m = 1; m <= 8; m <<= 1) {
#pragma unroll
    for (int r = 0; r < 4; ++r) {
      s1[r] += __shfl_xor(s1[r], m, 64);
      s2[r] += __shfl_xor(s2[r], m, 64);
    }
  }
  float mean[4], rstd[4];
#pragma unroll
  for (int r = 0; r < 4; ++r) {
    mean[r] = s1[r] * (1.f / C);
    float var = s2[r] * (1.f / C) - mean[r] * mean[r];
    rstd[r] = rsqrtf(var + 1e-5f);
  }
#pragma unroll
  for (int nt = 0; nt < 8; ++nt) {
    const int col = nt * 16 + r16;
    const float gmv = gamma[col], btv = beta[col];
#pragma unroll
    for (int r = 0; r < 4; ++r) {
      int row = tile_m + g * 4 + r;
      out[(size_t)row * C + col] = (acc[nt][r] - mean[r]) * rstd[r] * gmv + btv;
    }
  }
}

// ---------------- launch ----------------
extern "C" void kernel_launch(void* const* d_in, const int* in_sizes, int n_in,
                              void* d_out, int out_size, void* d_ws, size_t ws_size,
                              hipStream_t stream)
{
  const float* x        = (const float*)d_in[0];
  const int* ei         = (const int*)d_in[1];     // int32 from harness
  const float* Wp       = (const float*)d_in[2];
  const float* bp       = (const float*)d_in[3];
  const float* Wl       = (const float*)d_in[4];
  const float* bl       = (const float*)d_in[5];
  const float* Wr       = (const float*)d_in[6];
  const float* gamma    = (const float*)d_in[7];
  const float* beta     = (const float*)d_in[8];
  float* out            = (float*)d_out;

  char* ws = (char*)d_ws;
  uint16_t* xb   = (uint16_t*)(ws + 0);          // 25,600,000  x as bf16
  uint16_t* h    = (uint16_t*)(ws + 25600000);   // 25,600,000  relu(proj) bf16
  uint16_t* aggb = (uint16_t*)(ws + 51200000);   // 25,600,000  agg bf16
  uint32_t* ebuf = (uint32_t*)(ws + 51200000);   // 12,812,288  ALIASES aggb
  uint16_t* wpb  = (uint16_t*)(ws + 76800000);   // 32,768
  uint16_t* wlb  = (uint16_t*)(ws + 76832768);   // 32,768
  uint16_t* wrb  = (uint16_t*)(ws + 76865536);   // 32,768
  int* deg       = (int*)(ws + 76898304);        // 400,000
  int* start     = (int*)(ws + 77298304);        // 400,000
  int* gcnt      = (int*)(ws + 77698304);        // 3,128
  int* gbase     = (int*)(ws + 77702400);        // 3,128
  int* ssrc      = (int*)(ws + 78102400);        // 6,400,000

  const int* esrc = ei;        // edge_index[0]
  const int* edst = ei + NE;   // edge_index[1]

  hipMemsetAsync(gcnt, 0, NB * sizeof(int), stream);

  cast3_k<<<48, 256, 0, stream>>>(Wp, Wl, Wr, wpb, wlb, wrb);
  gemm_proj_k<<<MB, 512, 32768, stream>>>(x, wpb, bp, h, xb);

  phase1_k<<<250, 256, 0, stream>>>(esrc, edst, gcnt, ebuf);
  scan_block_k<<<1, 1024, 0, stream>>>(gcnt, gbase, NB);
  phase2_k<<<NB, 256, 0, stream>>>(ebuf, gcnt, gbase, ssrc, start, deg);

  aggregate_k<<<(NN + 3) / 4, 256, 0, stream>>>(h, ssrc, start, deg, aggb);

  gemm_out_k<<<MB, 512, 65536, stream>>>(aggb, xb, wlb, wrb, bl, gamma, beta, out);
}

// Round 6
// 136.479 us; speedup vs baseline: 2.9937x; 1.0896x over previous
//
#include <hip/hip_runtime.h>
#include <stdint.h>

#define NN 100000
#define NE 1600000
#define C  128
#define NB 782          // buckets of 128 dst nodes: 782*128 = 100096 >= NN
#define CAP 4096        // per-bucket edge capacity (mean 2048, sigma ~45)
#define SB_SHIFT 13     // src coarse-slice key in phase2 sort
#define MB 782          // GEMM blocks: 128 rows each
#define P1B 250         // phase1 blocks (6400 edges each)

typedef __attribute__((ext_vector_type(8))) short short8;
typedef __attribute__((ext_vector_type(4))) float f32x4;

__device__ __forceinline__ float bf2f(uint16_t u) {
  union { uint32_t u; float f; } v; v.u = ((uint32_t)u) << 16; return v.f;
}
__device__ __forceinline__ uint16_t f2bf(float f) {
  union { float f; uint32_t u; } v; v.f = f;
  uint32_t r = v.u + 0x7fffu + ((v.u >> 16) & 1u);   // RNE
  return (uint16_t)(r >> 16);
}

// ---------------- cast the 3 weight matrices in one dispatch ----------------
__global__ __launch_bounds__(256) void cast3_k(
    const float* __restrict__ a, const float* __restrict__ b, const float* __restrict__ c,
    uint16_t* __restrict__ oa, uint16_t* __restrict__ ob, uint16_t* __restrict__ oc)
{
  int i = blockIdx.x * 256 + threadIdx.x;     // 3 * 4096 float4-groups
  int which = i >> 12, j = i & 4095;
  const float* s = which == 0 ? a : (which == 1 ? b : c);
  uint16_t* d    = which == 0 ? oa : (which == 1 ? ob : oc);
  float4 v = ((const float4*)s)[j];
  uint2 p;
  p.x = (uint32_t)f2bf(v.x) | ((uint32_t)f2bf(v.y) << 16);
  p.y = (uint32_t)f2bf(v.z) | ((uint32_t)f2bf(v.w) << 16);
  ((uint2*)d)[j] = p;
}

// LDS weight tile: 16B chunk (c, k16) at byte c*256 + ((k16 ^ (c&15))<<4).
// Read of frag (c, kk, g) -> slot (kk*4+g)^(c&15): conflict-free b128 pattern.

// ------- fused front: blocks [0,MB) = GEMM1 (+x cast); [MB,MB+P1B) = phase1 -
// Independent work overlapped in one dispatch (stream would serialize them).
__global__ __launch_bounds__(512) void fused_front_k(
    const float* __restrict__ x, const uint16_t* __restrict__ wpb,
    const float* __restrict__ bias, uint16_t* __restrict__ h,
    uint16_t* __restrict__ xb,
    const int* __restrict__ esrc, const int* __restrict__ edst,
    int* __restrict__ gcnt, uint32_t* __restrict__ ebuf)
{
  extern __shared__ uint8_t slds[];
  const int t = threadIdx.x;

  if (blockIdx.x < MB) {
    // ---------------- GEMM1 role: h = relu(x @ Wp^T + bp) ----------------
#pragma unroll
    for (int q = 0; q < 4; ++q) {             // stage Wp: 2048 chunks of 16B
      int ci = q * 512 + t;
      int c = ci >> 4, k16 = ci & 15;
      *(short8*)(slds + c * 256 + ((k16 ^ (c & 15)) << 4)) =
          *(const short8*)(wpb + ci * 8);
    }
    __syncthreads();

    const int w = t >> 6, lane = t & 63;
    const int tile_m = blockIdx.x * 128 + w * 16;
    if (tile_m >= NN) return;
    const int r16 = lane & 15, g = lane >> 4;

    short8 a[4];
    const float* xp = x + (size_t)(tile_m + r16) * C + g * 8;
    uint16_t* xbp = xb + (size_t)(tile_m + r16) * C + g * 8;
#pragma unroll
    for (int kk = 0; kk < 4; ++kk) {
      float4 u = *(const float4*)(xp + kk * 32);
      float4 v = *(const float4*)(xp + kk * 32 + 4);
      short8 av;
      av[0] = (short)f2bf(u.x); av[1] = (short)f2bf(u.y);
      av[2] = (short)f2bf(u.z); av[3] = (short)f2bf(u.w);
      av[4] = (short)f2bf(v.x); av[5] = (short)f2bf(v.y);
      av[6] = (short)f2bf(v.z); av[7] = (short)f2bf(v.w);
      a[kk] = av;
      *(short8*)(xbp + kk * 32) = av;
    }

#pragma unroll
    for (int nt = 0; nt < 8; ++nt) {
      f32x4 acc = {0.f, 0.f, 0.f, 0.f};
      const int c = nt * 16 + r16;
      const uint8_t* rb = slds + c * 256;
#pragma unroll
      for (int kk = 0; kk < 4; ++kk) {
        short8 b = *(const short8*)(rb + ((((kk << 2) + g) ^ (c & 15)) << 4));
        acc = __builtin_amdgcn_mfma_f32_16x16x32_bf16(a[kk], b, acc, 0, 0, 0);
      }
      const float bv = bias[c];
#pragma unroll
      for (int r = 0; r < 4; ++r) {
        int row = tile_m + g * 4 + r;        // C/D: col=lane&15, row=(lane>>4)*4+r
        float v = acc[r] + bv;
        v = v > 0.f ? v : 0.f;
        h[(size_t)row * C + c] = f2bf(v);
      }
    }
  } else {
    // ---------------- phase1 role: bucket edges by dst>>7 ----------------
    int* bh = (int*)slds;                     // NB ints: histogram / cursor
    int* gb = bh + NB;                        // NB ints: reserved base
    const int blk = blockIdx.x - MB;
    const int base = blk * 6400;              // 1600 int4 per block

    for (int i = t; i < NB; i += 512) bh[i] = 0;

    const int4* ed4 = (const int4*)(edst + base);
    const int4* es4 = (const int4*)(esrc + base);
    int4 dv[4], sv[4];
    bool val[4];
#pragma unroll
    for (int k = 0; k < 4; ++k) {
      int i = t + k * 512;
      val[k] = (i < 1600);
      if (val[k]) { dv[k] = ed4[i]; sv[k] = es4[i]; }
    }
    __syncthreads();

#pragma unroll
    for (int k = 0; k < 4; ++k) if (val[k]) {
      atomicAdd(&bh[dv[k].x >> 7], 1); atomicAdd(&bh[dv[k].y >> 7], 1);
      atomicAdd(&bh[dv[k].z >> 7], 1); atomicAdd(&bh[dv[k].w >> 7], 1);
    }
    __syncthreads();

    for (int i = t; i < NB; i += 512) {
      int c = bh[i];
      gb[i] = c ? atomicAdd(&gcnt[i], c) : 0;
      bh[i] = 0;                              // reuse as local cursor
    }
    __syncthreads();

#define P1_SCATTER(d, s) do { \
      int bb = (d) >> 7; \
      int o = atomicAdd(&bh[bb], 1); \
      int pos = gb[bb] + o; \
      if (pos < CAP) ebuf[(size_t)bb * CAP + pos] = ((uint32_t)((d) & 127) << 17) | (uint32_t)(s); \
    } while (0)

#pragma unroll
    for (int k = 0; k < 4; ++k) if (val[k]) {
      P1_SCATTER(dv[k].x, sv[k].x); P1_SCATTER(dv[k].y, sv[k].y);
      P1_SCATTER(dv[k].z, sv[k].z); P1_SCATTER(dv[k].w, sv[k].w);
    }
#undef P1_SCATTER
  }
}

// ---------------- exclusive scan (1 block) over NB bucket counts ------------
__global__ __launch_bounds__(1024) void scan_block_k(
    const int* __restrict__ in, int* __restrict__ out, int n)
{
  __shared__ int sm[1024];
  int t = threadIdx.x;
  int v = (t < n) ? in[t] : 0;
  sm[t] = v;
  __syncthreads();
  for (int off = 1; off < 1024; off <<= 1) {
    int x = (t >= off) ? sm[t - off] : 0;
    __syncthreads();
    sm[t] += x;
    __syncthreads();
  }
  if (t < n) out[t] = sm[t] - v;            // exclusive
}

// ------- phase 2: per-bucket LDS sort by (local_dst, src>>13) ---------------
__global__ __launch_bounds__(256) void phase2_k(
    const uint32_t* __restrict__ ebuf, const int* __restrict__ gcnt,
    const int* __restrict__ gbase, int* __restrict__ ssrc,
    int* __restrict__ start, int* __restrict__ deg)
{
  __shared__ uint32_t raw[CAP];
  __shared__ int lout[CAP];
  __shared__ int cnt2[128 * 16];
  __shared__ int nd[128];
  const int b = blockIdx.x, t = threadIdx.x;
  const int n0 = b * 128;
  int cnt = gcnt[b]; if (cnt > CAP) cnt = CAP;
  const int base = gbase[b];

  for (int i = t; i < 128 * 16; i += 256) cnt2[i] = 0;
  __syncthreads();
  for (int i = t; i < cnt; i += 256) {
    uint32_t v = ebuf[(size_t)b * CAP + i];
    raw[i] = v;
    atomicAdd(&cnt2[(v >> 17) * 16 + ((v & 0x1FFFFu) >> SB_SHIFT)], 1);
  }
  __syncthreads();

  int deg_t = 0;
  if (t < 128) {
#pragma unroll
    for (int i = 0; i < 16; ++i) deg_t += cnt2[t * 16 + i];
    nd[t] = deg_t;
  }
  __syncthreads();
  for (int off = 1; off < 128; off <<= 1) {
    int v = 0;
    if (t < 128 && t >= off) v = nd[t - off];
    __syncthreads();
    if (t < 128) nd[t] += v;
    __syncthreads();
  }
  if (t < 128) {
    int pref = nd[t] - deg_t;               // exclusive
    if (n0 + t < NN) { start[n0 + t] = base + pref; deg[n0 + t] = deg_t; }
    int run = pref;
#pragma unroll
    for (int i = 0; i < 16; ++i) { int c = cnt2[t * 16 + i]; cnt2[t * 16 + i] = run; run += c; }
  }
  __syncthreads();
  for (int i = t; i < cnt; i += 256) {
    uint32_t v = raw[i];
    int o = atomicAdd(&cnt2[(v >> 17) * 16 + ((v & 0x1FFFFu) >> SB_SHIFT)], 1);
    lout[o] = (int)(v & 0x1FFFFu);
  }
  __syncthreads();
  for (int i = t; i < cnt; i += 256) ssrc[base + i] = lout[i];
}

// ------- aggregation: 1 wave/node, 16-lane edge groups, 16 edges in flight --
// lane = q*16 + l16: q = edge slot (0..3), l16 = channel group (8 ch, uint4).
__global__ __launch_bounds__(256) void aggregate_k(
    const uint16_t* __restrict__ h, const int* __restrict__ ssrc,
    const int* __restrict__ start, const int* __restrict__ deg,
    uint16_t* __restrict__ agg)
{
  const int wid = (blockIdx.x * 256 + threadIdx.x) >> 6;
  if (wid >= NN) return;
  const int lane = threadIdx.x & 63;
  const int q = lane >> 4;            // edge slot within group of 4
  const int l16 = lane & 15;          // channels l16*8 .. l16*8+7
  const int s0 = start[wid];
  const int cnt = deg[wid];
  const size_t choff = (size_t)l16 * 8;
  float a[8];
#pragma unroll
  for (int i = 0; i < 8; ++i) a[i] = 0.f;

#define ACC8(v) do { \
    a[0] += bf2f((uint16_t)(v).x); a[1] += bf2f((uint16_t)((v).x >> 16)); \
    a[2] += bf2f((uint16_t)(v).y); a[3] += bf2f((uint16_t)((v).y >> 16)); \
    a[4] += bf2f((uint16_t)(v).z); a[5] += bf2f((uint16_t)((v).z >> 16)); \
    a[6] += bf2f((uint16_t)(v).w); a[7] += bf2f((uint16_t)((v).w >> 16)); \
  } while (0)

  int j = 0;
  for (; j + 16 <= cnt; j += 16) {     // 16 edges in flight (4 uint4 loads/lane)
    int e0 = ssrc[s0 + j + q];
    int e1 = ssrc[s0 + j + 4 + q];
    int e2 = ssrc[s0 + j + 8 + q];
    int e3 = ssrc[s0 + j + 12 + q];
    uint4 v0 = *(const uint4*)(h + (size_t)e0 * C + choff);
    uint4 v1 = *(const uint4*)(h + (size_t)e1 * C + choff);
    uint4 v2 = *(const uint4*)(h + (size_t)e2 * C + choff);
    uint4 v3 = *(const uint4*)(h + (size_t)e3 * C + choff);
    ACC8(v0); ACC8(v1); ACC8(v2); ACC8(v3);
  }
  const int rem = cnt - j;             // 0..15, predicated, clamped idx (valid)
  if (rem > 0) {
    int i0 = (q      < rem) ? q      : 0;
    int i1 = (q + 4  < rem) ? q + 4  : 0;
    int i2 = (q + 8  < rem) ? q + 8  : 0;
    int i3 = (q + 12 < rem) ? q + 12 : 0;
    int e0 = ssrc[s0 + j + i0];
    int e1 = ssrc[s0 + j + i1];
    int e2 = ssrc[s0 + j + i2];
    int e3 = ssrc[s0 + j + i3];
    uint4 v0 = *(const uint4*)(h + (size_t)e0 * C + choff);
    uint4 v1 = *(const uint4*)(h + (size_t)e1 * C + choff);
    uint4 v2 = *(const uint4*)(h + (size_t)e2 * C + choff);
    uint4 v3 = *(const uint4*)(h + (size_t)e3 * C + choff);
    if (q < rem)      ACC8(v0);
    if (q + 4 < rem)  ACC8(v1);
    if (q + 8 < rem)  ACC8(v2);
    if (q + 12 < rem) ACC8(v3);
  }
#undef ACC8

#pragma unroll
  for (int i = 0; i < 8; ++i) {        // combine the 4 edge slots
    a[i] += __shfl_xor(a[i], 16, 64);
    a[i] += __shfl_xor(a[i], 32, 64);
  }
  if (q == 0) {
    uint4 p;
    p.x = (uint32_t)f2bf(a[0]) | ((uint32_t)f2bf(a[1]) << 16);
    p.y = (uint32_t)f2bf(a[2]) | ((uint32_t)f2bf(a[3]) << 16);
    p.z = (uint32_t)f2bf(a[4]) | ((uint32_t)f2bf(a[5]) << 16);
    p.w = (uint32_t)f2bf(a[6]) | ((uint32_t)f2bf(a[7]) << 16);
    *(uint4*)(agg + (size_t)wid * C + choff) = p;
  }
}

// ---------------- GEMM2 + LayerNorm fused; Wl+Wr staged in 64 KB LDS --------
__global__ __launch_bounds__(512) void gemm_out_k(
    const uint16_t* __restrict__ aggb, const uint16_t* __restrict__ xb,
    const uint16_t* __restrict__ wlb, const uint16_t* __restrict__ wrb,
    const float* __restrict__ bl, const float* __restrict__ gamma,
    const float* __restrict__ beta, float* __restrict__ out)
{
  extern __shared__ uint8_t slds[];
  const int t = threadIdx.x;
#pragma unroll
  for (int q = 0; q < 4; ++q) {               // Wl: 2048 chunks
    int ci = q * 512 + t;
    int c = ci >> 4, k16 = ci & 15;
    *(short8*)(slds + c * 256 + ((k16 ^ (c & 15)) << 4)) =
        *(const short8*)(wlb + ci * 8);
  }
#pragma unroll
  for (int q = 0; q < 4; ++q) {               // Wr: 2048 chunks at +32KB
    int ci = q * 512 + t;
    int c = ci >> 4, k16 = ci & 15;
    *(short8*)(slds + 32768 + c * 256 + ((k16 ^ (c & 15)) << 4)) =
        *(const short8*)(wrb + ci * 8);
  }
  __syncthreads();

  const int w = t >> 6, lane = t & 63;
  const int tile_m = blockIdx.x * 128 + w * 16;
  if (tile_m >= NN) return;
  const int r16 = lane & 15, g = lane >> 4;

  short8 a0[4], a1[4];
  const uint16_t* p0 = aggb + (size_t)(tile_m + r16) * C + g * 8;
  const uint16_t* p1 = xb   + (size_t)(tile_m + r16) * C + g * 8;
#pragma unroll
  for (int kk = 0; kk < 4; ++kk) {
    a0[kk] = *(const short8*)(p0 + kk * 32);
    a1[kk] = *(const short8*)(p1 + kk * 32);
  }

  f32x4 acc[8];
#pragma unroll
  for (int nt = 0; nt < 8; ++nt) {
    f32x4 c4 = {0.f, 0.f, 0.f, 0.f};
    const int c = nt * 16 + r16;
    const uint8_t* rbl = slds + c * 256;
    const uint8_t* rbr = slds + 32768 + c * 256;
#pragma unroll
    for (int kk = 0; kk < 4; ++kk) {
      short8 b = *(const short8*)(rbl + ((((kk << 2) + g) ^ (c & 15)) << 4));
      c4 = __builtin_amdgcn_mfma_f32_16x16x32_bf16(a0[kk], b, c4, 0, 0, 0);
    }
#pragma unroll
    for (int kk = 0; kk < 4; ++kk) {
      short8 b = *(const short8*)(rbr + ((((kk << 2) + g) ^ (c & 15)) << 4));
      c4 = __builtin_amdgcn_mfma_f32_16x16x32_bf16(a1[kk], b, c4, 0, 0, 0);
    }
    const float bv = bl[c];
#pragma unroll
    for (int r = 0; r < 4; ++r) c4[r] += bv;
    acc[nt] = c4;
  }

  // LayerNorm: each row lives in one 16-lane group -> shfl_xor 1,2,4,8
  float s1[4], s2[4];
#pragma unroll
  for (int r = 0; r < 4; ++r) { s1[r] = 0.f; s2[r] = 0.f; }
#pragma unroll
  for (int nt = 0; nt < 8; ++nt)
#pragma unroll
    for (int r = 0; r < 4; ++r) { float v = acc[nt][r]; s1[r] += v; s2[r] += v * v; }
#pragma unroll
  for (int m = 1; m <= 8; m <<= 1) {
#pragma unroll
    for (int r = 0; r < 4; ++r) {
      s1[r] += __shfl_xor(s1[r], m, 64);
      s2[r] += __shfl_xor(s2[r], m, 64);
    }
  }
  float mean[4], rstd[4];
#pragma unroll
  for (int r = 0; r < 4; ++r) {
    mean[r] = s1[r] * (1.f / C);
    float var = s2[r] * (1.f / C) - mean[r] * mean[r];
    rstd[r] = rsqrtf(var + 1e-5f);
  }
#pragma unroll
  for (int nt = 0; nt < 8; ++nt) {
    const int col = nt * 16 + r16;
    const float gmv = gamma[col], btv = beta[col];
#pragma unroll
    for (int r = 0; r < 4; ++r) {
      int row = tile_m + g * 4 + r;
      out[(size_t)row * C + col] = (acc[nt][r] - mean[r]) * rstd[r] * gmv + btv;
    }
  }
}

// ---------------- launch ----------------
extern "C" void kernel_launch(void* const* d_in, const int* in_sizes, int n_in,
                              void* d_out, int out_size, void* d_ws, size_t ws_size,
                              hipStream_t stream)
{
  const float* x        = (const float*)d_in[0];
  const int* ei         = (const int*)d_in[1];     // int32 from harness
  const float* Wp       = (const float*)d_in[2];
  const float* bp       = (const float*)d_in[3];
  const float* Wl       = (const float*)d_in[4];
  const float* bl       = (const float*)d_in[5];
  const float* Wr       = (const float*)d_in[6];
  const float* gamma    = (const float*)d_in[7];
  const float* beta     = (const float*)d_in[8];
  float* out            = (float*)d_out;

  char* ws = (char*)d_ws;
  uint16_t* xb   = (uint16_t*)(ws + 0);          // 25,600,000  x as bf16
  uint16_t* h    = (uint16_t*)(ws + 25600000);   // 25,600,000  relu(proj) bf16
  uint16_t* aggb = (uint16_t*)(ws + 51200000);   // 25,600,000  agg bf16
  uint32_t* ebuf = (uint32_t*)(ws + 51200000);   // 12,812,288  ALIASES aggb
  uint16_t* wpb  = (uint16_t*)(ws + 76800000);   // 32,768
  uint16_t* wlb  = (uint16_t*)(ws + 76832768);   // 32,768
  uint16_t* wrb  = (uint16_t*)(ws + 76865536);   // 32,768
  int* deg       = (int*)(ws + 76898304);        // 400,000
  int* start     = (int*)(ws + 77298304);        // 400,000
  int* gcnt      = (int*)(ws + 77698304);        // 3,128
  int* gbase     = (int*)(ws + 77702400);        // 3,128
  int* ssrc      = (int*)(ws + 78102400);        // 6,400,000

  const int* esrc = ei;        // edge_index[0]
  const int* edst = ei + NE;   // edge_index[1]

  hipMemsetAsync(gcnt, 0, NB * sizeof(int), stream);

  cast3_k<<<48, 256, 0, stream>>>(Wp, Wl, Wr, wpb, wlb, wrb);

  fused_front_k<<<MB + P1B, 512, 32768, stream>>>(
      x, wpb, bp, h, xb, esrc, edst, gcnt, ebuf);

  scan_block_k<<<1, 1024, 0, stream>>>(gcnt, gbase, NB);
  phase2_k<<<NB, 256, 0, stream>>>(ebuf, gcnt, gbase, ssrc, start, deg);

  aggregate_k<<<(NN + 3) / 4, 256, 0, stream>>>(h, ssrc, start, deg, aggb);

  gemm_out_k<<<MB, 512, 65536, stream>>>(aggb, xb, wlb, wrb, bl, gamma, beta, out);
}